// Round 11
// baseline (501.167 us; speedup 1.0000x reference)
//
#include <hip/hip_runtime.h>
#include <hip/hip_bf16.h>
#include <cfloat>

#define N_NODES 50000
#define N_EDGES 800000
#define N_GRAPHS 50
#define FEAT 256
#define NEG_SLOPE 0.2f

typedef __attribute__((ext_vector_type(8))) short short8;
typedef __attribute__((ext_vector_type(4))) float floatx4;

__device__ __forceinline__ float lrelu(float e) {
  return e > 0.f ? e : NEG_SLOPE * e;
}
__device__ __forceinline__ short f2bf(float f) {
  __hip_bfloat16 b = __float2bfloat16(f);
  return *(short*)&b;
}
__device__ __forceinline__ float bf2f(short s) {
  unsigned u = ((unsigned)(unsigned short)s) << 16;
  return __uint_as_float(u);
}

// ---- W prep (blocks 0..511) + dst histogram (blocks 512..) ----
__global__ __launch_bounds__(256) void wsplit_hist_kernel(
    const float* __restrict__ W1, const float* __restrict__ W2,
    short* __restrict__ H1, short* __restrict__ L1,
    short* __restrict__ H2, short* __restrict__ L2,
    const int* __restrict__ dst, int* __restrict__ cnt) {
  int b = blockIdx.x, t = threadIdx.x;
  if (b < 512) {
    const float* W = (b < 256) ? W1 : W2;
    short* Hp = (b < 256) ? H1 : H2;
    short* Lp = (b < 256) ? L1 : L2;
    int k = b & 255;
    float v = W[k * 256 + t];
    short h = f2bf(v);
    Hp[t * 256 + k] = h;
    Lp[t * 256 + k] = f2bf(v - bf2f(h));
  } else {
    int e = (b - 512) * 256 + t;
    if (e < N_EDGES) atomicAdd(&cnt[dst[e]], 1);
  }
}

// ---- block reduction of cnt -> bsum; block 0 also computes graph bounds ----
__global__ __launch_bounds__(256) void scan_partial_kernel(
    const int* __restrict__ cnt, int* __restrict__ bsum, int n,
    const int* __restrict__ batch, int* __restrict__ gstart) {
  __shared__ int buf[256];
  int t = threadIdx.x;
  int i = blockIdx.x * 256 + t;
  buf[t] = (i < n) ? cnt[i] : 0;
  __syncthreads();
  for (int off = 128; off >= 1; off >>= 1) {
    if (t < off) buf[t] += buf[t + off];
    __syncthreads();
  }
  if (t == 0) bsum[blockIdx.x] = buf[0];
  if (blockIdx.x == 0 && t <= N_GRAPHS) {
    int lo = 0, hi = N_NODES;
    while (lo < hi) {
      int mid = (lo + hi) >> 1;
      if (batch[mid] < t) lo = mid + 1; else hi = mid;
    }
    gstart[t] = lo;
  }
}

// ---- final scan: each block re-scans the block-sums in LDS ----
__global__ __launch_bounds__(256) void scan_final_kernel(
    const int* __restrict__ cnt, const int* __restrict__ bsum,
    int* __restrict__ offs, int* __restrict__ cursor, int n, int nb) {
  __shared__ int buf[256], sb[256];
  int t = threadIdx.x;
  int i = blockIdx.x * 256 + t;
  int v = (i < n) ? cnt[i] : 0;
  buf[t] = v;
  sb[t] = (t < nb) ? bsum[t] : 0;
  __syncthreads();
  for (int off = 1; off < 256; off <<= 1) {
    int y1 = (t >= off) ? buf[t - off] : 0;
    int y2 = (t >= off) ? sb[t - off] : 0;
    __syncthreads();
    buf[t] += y1;
    sb[t] += y2;
    __syncthreads();
  }
  int carry = (blockIdx.x > 0) ? sb[blockIdx.x - 1] : 0;
  int excl = buf[t] - v + carry;
  if (i < n) { offs[i] = excl; cursor[i] = excl; }
  if (blockIdx.x == 0 && t == 0) offs[N_NODES] = sb[nb - 1];
}

// ---- no-LDS single-wave MFMA GEMM + fused attention dots ----
// 64x64 tile per 64-thread block; A and B fragments loaded DIRECTLY from
// global in MFMA operand layout (A: lane&15=row, 8 fp32 at k=(lane>>4)*8;
// B: Wt[col][k] row-major -> one short8 per lane). Zero LDS, zero barriers;
// 3128 blocks give ~12 waves/CU and the compiler pipelines loads freely.
// 3-term split: C = Ah*Bh + Ah*Bl + Al*Bh. Layer-1 blocks also run the
// counting-sort scatter as a prologue (256 edges/block, overlapped).
template <int H>
__global__ __launch_bounds__(64, 3) void gemm_mfma_kernel(
    const float* __restrict__ A, const short* __restrict__ WtH,
    const short* __restrict__ WtL, short* __restrict__ C16,
    const float* __restrict__ att_src, const float* __restrict__ att_dst,
    float* __restrict__ a_src, float* __restrict__ a_dst, int M,
    const int* __restrict__ esrc, const int* __restrict__ edst,
    int* __restrict__ cursor, int* __restrict__ ssrc) {
  int t = threadIdx.x;  // 0..63
  if (esrc != nullptr) {
    int base = (blockIdx.y * gridDim.x + blockIdx.x) * 256 + t;
#pragma unroll
    for (int j = 0; j < 4; j++) {
      int e = base + j * 64;
      if (e < N_EDGES) {
        int d = edst[e];
        int pos = atomicAdd(&cursor[d], 1);
        ssrc[pos] = esrc[e];
      }
    }
  }
  int bm = blockIdx.y * 64, bn = blockIdx.x * 64;
  int m15 = t & 15, q = t >> 4;
  floatx4 acc[4][4] = {};
  // A rows for each r-tile (clamped for the M tail; stores are guarded)
  int arow[4];
#pragma unroll
  for (int r = 0; r < 4; r++) {
    int row = bm + r * 16 + m15;
    arow[r] = row < M ? row : M - 1;
  }
  const short* bhbase = WtH + (size_t)(bn + m15) * 256 + q * 8;
  const short* blbase = WtL + (size_t)(bn + m15) * 256 + q * 8;
  for (int k0 = 0; k0 < 256; k0 += 32) {
    short8 Bh[4], Bl[4];
#pragma unroll
    for (int c = 0; c < 4; c++) {
      Bh[c] = *(const short8*)(bhbase + (size_t)c * 16 * 256 + k0);
      Bl[c] = *(const short8*)(blbase + (size_t)c * 16 * 256 + k0);
    }
#pragma unroll
    for (int r = 0; r < 4; r++) {
      const float* ap = A + (size_t)arow[r] * 256 + k0 + q * 8;
      float4 a0 = *(const float4*)(ap + 0);
      float4 a1 = *(const float4*)(ap + 4);
      float av[8];
      *(float4*)&av[0] = a0;
      *(float4*)&av[4] = a1;
      short8 Ah, Al;
#pragma unroll
      for (int j = 0; j < 8; j++) {
        short h = f2bf(av[j]);
        Ah[j] = h;
        Al[j] = f2bf(av[j] - bf2f(h));
      }
#pragma unroll
      for (int c = 0; c < 4; c++) {
        acc[r][c] = __builtin_amdgcn_mfma_f32_16x16x32_bf16(Ah, Bh[c], acc[r][c], 0, 0, 0);
        acc[r][c] = __builtin_amdgcn_mfma_f32_16x16x32_bf16(Ah, Bl[c], acc[r][c], 0, 0, 0);
        acc[r][c] = __builtin_amdgcn_mfma_f32_16x16x32_bf16(Al, Bh[c], acc[r][c], 0, 0, 0);
      }
    }
  }
  // epilogue: C/D layout col=lane&15, row=q*4+reg (verified m89/m91)
  float asv[4], adv[4];
#pragma unroll
  for (int c = 0; c < 4; c++) {
    int col = bn + c * 16 + m15;
    asv[c] = att_src[col];
    adv[c] = att_dst[col];
  }
#pragma unroll
  for (int r = 0; r < 4; r++) {
#pragma unroll
    for (int p = 0; p < 4; p++) {
      int grow = bm + r * 16 + q * 4 + p;
      float s = acc[r][0][p] * asv[0] + acc[r][1][p] * asv[1] +
                acc[r][2][p] * asv[2] + acc[r][3][p] * asv[3];
      float d = acc[r][0][p] * adv[0] + acc[r][1][p] * adv[1] +
                acc[r][2][p] * adv[2] + acc[r][3][p] * adv[3];
#pragma unroll
      for (int o = 1; o < 16; o <<= 1) {
        s += __shfl_xor(s, o, 64);
        d += __shfl_xor(d, o, 64);
      }
      if (grow < M) {
        if (m15 == 0) {
          if constexpr (H == 4) {
            int head = bn >> 6;  // 64-col block == one full head
            a_src[grow * 4 + head] = s;
            a_dst[grow * 4 + head] = d;
          } else {
            atomicAdd(&a_src[grow], s);
            atomicAdd(&a_dst[grow], d);
          }
        }
#pragma unroll
        for (int c = 0; c < 4; c++) {
          int gcol = bn + c * 16 + m15;
          C16[(size_t)grow * 256 + gcol] = f2bf(acc[r][c][p]);
        }
      }
    }
  }
}

// ---- fully fused aggregate: in-register softmax (max-free), 1 wave/node ----
template <int CH>
__global__ __launch_bounds__(128) void agg_kernel(
    const short* __restrict__ h16, const float* __restrict__ a_src,
    const float* __restrict__ a_dst, const int* __restrict__ offs,
    const int* __restrict__ ssrc, const float* __restrict__ bias,
    float* __restrict__ out, float* __restrict__ z1, float* __restrict__ z2) {
  constexpr int H = 256 / CH;
  int n = blockIdx.x * 2 + (threadIdx.x >> 6);
  int lane = threadIdx.x & 63;
  if (n >= N_NODES) return;
  int head = (4 * lane) / CH;
  int start = offs[n], end = offs[n + 1];
  float adv = a_dst[n * H + head];
  if (z1 != nullptr && lane == 0) { z1[n] = 0.f; z2[n] = 0.f; }
  float l = 0.f;
  float acc0 = 0.f, acc1 = 0.f, acc2 = 0.f, acc3 = 0.f;
  int i = start;
  for (; i + 8 <= end; i += 8) {
    int s[8]; uint2 u[8]; float av[8];
#pragma unroll
    for (int j = 0; j < 8; j++) s[j] = ssrc[i + j];
#pragma unroll
    for (int j = 0; j < 8; j++)
      u[j] = *(const uint2*)(h16 + (size_t)s[j] * 256 + 4 * lane);
#pragma unroll
    for (int j = 0; j < 8; j++) av[j] = a_src[s[j] * H + head];
#pragma unroll
    for (int j = 0; j < 8; j++) {
      float p = __expf(lrelu(av[j] + adv));
      l += p;
      acc0 = fmaf(p, __uint_as_float(u[j].x << 16), acc0);
      acc1 = fmaf(p, __uint_as_float(u[j].x & 0xffff0000u), acc1);
      acc2 = fmaf(p, __uint_as_float(u[j].y << 16), acc2);
      acc3 = fmaf(p, __uint_as_float(u[j].y & 0xffff0000u), acc3);
    }
  }
  for (; i < end; i++) {
    int s = ssrc[i];
    uint2 u = *(const uint2*)(h16 + (size_t)s * 256 + 4 * lane);
    float p = __expf(lrelu(a_src[s * H + head] + adv));
    l += p;
    acc0 = fmaf(p, __uint_as_float(u.x << 16), acc0);
    acc1 = fmaf(p, __uint_as_float(u.x & 0xffff0000u), acc1);
    acc2 = fmaf(p, __uint_as_float(u.y << 16), acc2);
    acc3 = fmaf(p, __uint_as_float(u.y & 0xffff0000u), acc3);
  }
  float ilv = l > 0.f ? 1.f / l : 0.f;
  float4 bv = *(const float4*)(bias + 4 * lane);
  float4 o;
  o.x = fmaxf(fmaf(acc0, ilv, bv.x), 0.f);
  o.y = fmaxf(fmaf(acc1, ilv, bv.y), 0.f);
  o.z = fmaxf(fmaf(acc2, ilv, bv.z), 0.f);
  o.w = fmaxf(fmaf(acc3, ilv, bv.w), 0.f);
  *(float4*)(out + (size_t)n * 256 + 4 * lane) = o;
}

// ---- global mean pool + FC ----
#define POOL_PARTS 16
__global__ __launch_bounds__(256) void pool_partial_kernel(
    const float* __restrict__ h, const int* __restrict__ gstart,
    float* __restrict__ part) {
  int g = blockIdx.x, p = blockIdx.y, t = threadIdx.x;
  int s = gstart[g], e = gstart[g + 1];
  float acc = 0.f;
  for (int n = s + p; n < e; n += POOL_PARTS) acc += h[(size_t)n * 256 + t];
  part[((size_t)g * POOL_PARTS + p) * 256 + t] = acc;
}

__global__ __launch_bounds__(256) void poolfc_kernel(
    const float* __restrict__ part, const int* __restrict__ gstart,
    const float* __restrict__ W, const float* __restrict__ b,
    float* __restrict__ out) {
  int g = blockIdx.x, t = threadIdx.x;
  __shared__ float ps[256];
  float acc = 0.f;
#pragma unroll
  for (int p = 0; p < POOL_PARTS; p++)
    acc += part[((size_t)g * POOL_PARTS + p) * 256 + t];
  int cnt = gstart[g + 1] - gstart[g];
  ps[t] = acc / (float)(cnt > 0 ? cnt : 1);
  __syncthreads();
  float a2 = 0.f;
#pragma unroll 8
  for (int k = 0; k < 256; k++) a2 = fmaf(ps[k], W[k * 256 + t], a2);
  out[g * 256 + t] = fmaxf(a2 + b[t], 0.f);
}

extern "C" void kernel_launch(void* const* d_in, const int* in_sizes, int n_in,
                              void* d_out, int out_size, void* d_ws, size_t ws_size,
                              hipStream_t stream) {
  const float* x      = (const float*)d_in[0];
  const int*   ei     = (const int*)d_in[1];
  const int*   batch  = (const int*)d_in[2];
  const float* W1     = (const float*)d_in[3];
  const float* att_s1 = (const float*)d_in[4];
  const float* att_d1 = (const float*)d_in[5];
  const float* b1     = (const float*)d_in[6];
  const float* W2     = (const float*)d_in[7];
  const float* att_s2 = (const float*)d_in[8];
  const float* att_d2 = (const float*)d_in[9];
  const float* b2     = (const float*)d_in[10];
  const float* Wfc    = (const float*)d_in[11];
  const float* bfc    = (const float*)d_in[12];
  const int* src = ei;
  const int* dst = ei + N_EDGES;
  float* outp = (float*)d_out;

  char* ws = (char*)d_ws;
  size_t off = 0;
  auto alloc = [&](size_t bytes) -> char* {
    char* p = ws + off;
    off += (bytes + 255) & ~(size_t)255;
    return p;
  };
  float* x2_buf = (float*)alloc((size_t)N_NODES * FEAT * 4);
  short* h16    = (short*)alloc((size_t)N_NODES * FEAT * 2);
  float* as_buf = (float*)alloc((size_t)N_NODES * 4 * 4);
  float* ad_buf = (float*)alloc((size_t)N_NODES * 4 * 4);
  float* as2    = (float*)alloc((size_t)N_NODES * 4);
  float* ad2    = (float*)alloc((size_t)N_NODES * 4);
  float* part   = (float*)alloc((size_t)N_GRAPHS * POOL_PARTS * FEAT * 4);
  short* WtH1   = (short*)alloc((size_t)256 * 256 * 2);
  short* WtL1   = (short*)alloc((size_t)256 * 256 * 2);
  short* WtH2   = (short*)alloc((size_t)256 * 256 * 2);
  short* WtL2   = (short*)alloc((size_t)256 * 256 * 2);
  int* cnt    = (int*)alloc((size_t)N_NODES * 4);
  int* offs   = (int*)alloc((size_t)(N_NODES + 1) * 4);
  int* cursor = (int*)alloc((size_t)N_NODES * 4);
  int* ssrc   = (int*)alloc((size_t)N_EDGES * 4);
  int* bsum   = (int*)alloc((size_t)256 * 4);
  int* gstart = (int*)alloc((size_t)(N_GRAPHS + 1) * 4);

  int eb = (N_EDGES + 255) / 256;   // 3125
  int nb = (N_NODES + 255) / 256;   // 196
  int gy = (N_NODES + 63) / 64;     // 782

  hipMemsetAsync(cnt, 0, (size_t)N_NODES * 4, stream);
  wsplit_hist_kernel<<<512 + eb, 256, 0, stream>>>(W1, W2, WtH1, WtL1, WtH2, WtL2,
                                                   dst, cnt);
  scan_partial_kernel<<<nb, 256, 0, stream>>>(cnt, bsum, N_NODES, batch, gstart);
  scan_final_kernel<<<nb, 256, 0, stream>>>(cnt, bsum, offs, cursor, N_NODES, nb);

  dim3 gg(4, gy);  // 3128 single-wave blocks
  // layer 1: scatter prologue + gemm + att epilogue
  gemm_mfma_kernel<4><<<gg, 64, 0, stream>>>(x, WtH1, WtL1, h16,
                                             att_s1, att_d1, as_buf, ad_buf,
                                             N_NODES, src, dst, cursor, ssrc);
  agg_kernel<64><<<N_NODES / 2, 128, 0, stream>>>(h16, as_buf, ad_buf, offs, ssrc,
                                                  b1, x2_buf, as2, ad2);
  // layer 2: H=1 (as2/ad2 pre-zeroed by layer-1 agg)
  gemm_mfma_kernel<1><<<gg, 64, 0, stream>>>(x2_buf, WtH2, WtL2, h16,
                                             att_s2, att_d2, as2, ad2,
                                             N_NODES, nullptr, nullptr,
                                             nullptr, nullptr);
  agg_kernel<256><<<N_NODES / 2, 128, 0, stream>>>(h16, as2, ad2, offs, ssrc,
                                                   b2, x2_buf, nullptr, nullptr);
  pool_partial_kernel<<<dim3(N_GRAPHS, POOL_PARTS), 256, 0, stream>>>(x2_buf, gstart, part);
  poolfc_kernel<<<N_GRAPHS, 256, 0, stream>>>(part, gstart, Wfc, bfc, outp);
}

// Round 12
// 473.880 us; speedup vs baseline: 1.0576x; 1.0576x over previous
//
#include <hip/hip_runtime.h>
#include <hip/hip_bf16.h>
#include <cfloat>

#define N_NODES 50000
#define N_EDGES 800000
#define N_GRAPHS 50
#define FEAT 256
#define NEG_SLOPE 0.2f

typedef __attribute__((ext_vector_type(8))) short short8;
typedef __attribute__((ext_vector_type(4))) float floatx4;

__device__ __forceinline__ float lrelu(float e) {
  return e > 0.f ? e : NEG_SLOPE * e;
}
__device__ __forceinline__ short f2bf(float f) {
  __hip_bfloat16 b = __float2bfloat16(f);
  return *(short*)&b;
}
__device__ __forceinline__ float bf2f(short s) {
  unsigned u = ((unsigned)(unsigned short)s) << 16;
  return __uint_as_float(u);
}

// ---- W prep (blocks 0..511) + dst histogram (blocks 512..) ----
__global__ __launch_bounds__(256) void wsplit_hist_kernel(
    const float* __restrict__ W1, const float* __restrict__ W2,
    short* __restrict__ H1, short* __restrict__ L1,
    short* __restrict__ H2, short* __restrict__ L2,
    const int* __restrict__ dst, int* __restrict__ cnt) {
  int b = blockIdx.x, t = threadIdx.x;
  if (b < 512) {
    const float* W = (b < 256) ? W1 : W2;
    short* Hp = (b < 256) ? H1 : H2;
    short* Lp = (b < 256) ? L1 : L2;
    int k = b & 255;
    float v = W[k * 256 + t];
    short h = f2bf(v);
    Hp[t * 256 + k] = h;
    Lp[t * 256 + k] = f2bf(v - bf2f(h));
  } else {
    int e = (b - 512) * 256 + t;
    if (e < N_EDGES) atomicAdd(&cnt[dst[e]], 1);
  }
}

// ---- block reduction of cnt -> bsum; block 0 also computes graph bounds ----
__global__ __launch_bounds__(256) void scan_partial_kernel(
    const int* __restrict__ cnt, int* __restrict__ bsum, int n,
    const int* __restrict__ batch, int* __restrict__ gstart) {
  __shared__ int buf[256];
  int t = threadIdx.x;
  int i = blockIdx.x * 256 + t;
  buf[t] = (i < n) ? cnt[i] : 0;
  __syncthreads();
  for (int off = 128; off >= 1; off >>= 1) {
    if (t < off) buf[t] += buf[t + off];
    __syncthreads();
  }
  if (t == 0) bsum[blockIdx.x] = buf[0];
  if (blockIdx.x == 0 && t <= N_GRAPHS) {
    int lo = 0, hi = N_NODES;
    while (lo < hi) {
      int mid = (lo + hi) >> 1;
      if (batch[mid] < t) lo = mid + 1; else hi = mid;
    }
    gstart[t] = lo;
  }
}

// ---- final scan: each block re-scans the block-sums in LDS ----
__global__ __launch_bounds__(256) void scan_final_kernel(
    const int* __restrict__ cnt, const int* __restrict__ bsum,
    int* __restrict__ offs, int* __restrict__ cursor, int n, int nb) {
  __shared__ int buf[256], sb[256];
  int t = threadIdx.x;
  int i = blockIdx.x * 256 + t;
  int v = (i < n) ? cnt[i] : 0;
  buf[t] = v;
  sb[t] = (t < nb) ? bsum[t] : 0;
  __syncthreads();
  for (int off = 1; off < 256; off <<= 1) {
    int y1 = (t >= off) ? buf[t - off] : 0;
    int y2 = (t >= off) ? sb[t - off] : 0;
    __syncthreads();
    buf[t] += y1;
    sb[t] += y2;
    __syncthreads();
  }
  int carry = (blockIdx.x > 0) ? sb[blockIdx.x - 1] : 0;
  int excl = buf[t] - v + carry;
  if (i < n) { offs[i] = excl; cursor[i] = excl; }
  if (blockIdx.x == 0 && t == 0) offs[N_NODES] = sb[nb - 1];
}

// ---- MFMA GEMM: A staged in LDS (bf16 hi/lo split), B DIRECT from L2 ----
// BM=BN=128, 4 waves (2x2 of 64x64). B-fragments load as contiguous short8
// from the pre-transposed 256KB L2-resident Wt (no LDS round-trip): halves
// LDS traffic/staging vs the 4-buffer design. 3-term split. Layer-1 blocks
// run the counting-sort scatter as a prologue (1024 edges/block).
template <int H>
__global__ __launch_bounds__(256) void gemm_mfma_kernel(
    const float* __restrict__ A, const short* __restrict__ WtH,
    const short* __restrict__ WtL, short* __restrict__ C16,
    const float* __restrict__ att_src, const float* __restrict__ att_dst,
    float* __restrict__ a_src, float* __restrict__ a_dst, int M,
    const int* __restrict__ esrc, const int* __restrict__ edst,
    int* __restrict__ cursor, int* __restrict__ ssrc) {
  int t = threadIdx.x;
  if (esrc != nullptr) {
    int base = (blockIdx.y * 2 + blockIdx.x) * 1024 + t;
#pragma unroll
    for (int j = 0; j < 4; j++) {
      int e = base + j * 256;
      if (e < N_EDGES) {
        int d = edst[e];
        int pos = atomicAdd(&cursor[d], 1);
        ssrc[pos] = esrc[e];
      }
    }
  }
  __shared__ short AsH[128][40], AsL[128][40];  // 20 KB
  int bm = blockIdx.y * 128, bn = blockIdx.x * 128;
  int w = t >> 6, lane = t & 63;
  int wrow = (w & 1) * 64, wcol = (w >> 1) * 64;
  int m15 = lane & 15, q = lane >> 4;
  int sr = t >> 1, sk = (t & 1) * 16;
  floatx4 acc[4][4] = {};
  int arow = bm + sr;
  bool avalid = arow < M;
  const short* bhbase = WtH + (size_t)(bn + wcol + m15) * 256 + q * 8;
  const short* blbase = WtL + (size_t)(bn + wcol + m15) * 256 + q * 8;
  for (int k0 = 0; k0 < 256; k0 += 32) {
    // B fragments direct from global (L2-resident weights)
    short8 Bh[4], Bl[4];
#pragma unroll
    for (int c = 0; c < 4; c++) {
      Bh[c] = *(const short8*)(bhbase + (size_t)c * 16 * 256 + k0);
      Bl[c] = *(const short8*)(blbase + (size_t)c * 16 * 256 + k0);
    }
    // A tile -> registers -> bf16 hi/lo -> LDS
    float4 a0 = make_float4(0.f, 0.f, 0.f, 0.f), a1 = a0, a2 = a0, a3 = a0;
    if (avalid) {
      const float* Ap = A + (size_t)arow * 256 + k0 + sk;
      a0 = *(const float4*)(Ap + 0);
      a1 = *(const float4*)(Ap + 4);
      a2 = *(const float4*)(Ap + 8);
      a3 = *(const float4*)(Ap + 12);
    }
    float af[16];
    *(float4*)&af[0] = a0; *(float4*)&af[4] = a1;
    *(float4*)&af[8] = a2; *(float4*)&af[12] = a3;
    short th[16], tl[16];
#pragma unroll
    for (int j = 0; j < 16; j++) {
      short h = f2bf(af[j]);
      th[j] = h;
      tl[j] = f2bf(af[j] - bf2f(h));
    }
    __syncthreads();  // prior iter's LDS reads complete
    *(int4*)&AsH[sr][sk + 0] = *(int4*)&th[0];
    *(int4*)&AsH[sr][sk + 8] = *(int4*)&th[8];
    *(int4*)&AsL[sr][sk + 0] = *(int4*)&tl[0];
    *(int4*)&AsL[sr][sk + 8] = *(int4*)&tl[8];
    __syncthreads();
#pragma unroll
    for (int r = 0; r < 4; r++) {
      short8 Ah = *(const short8*)&AsH[wrow + r * 16 + m15][q * 8];
      short8 Al = *(const short8*)&AsL[wrow + r * 16 + m15][q * 8];
#pragma unroll
      for (int c = 0; c < 4; c++) {
        acc[r][c] = __builtin_amdgcn_mfma_f32_16x16x32_bf16(Ah, Bh[c], acc[r][c], 0, 0, 0);
        acc[r][c] = __builtin_amdgcn_mfma_f32_16x16x32_bf16(Ah, Bl[c], acc[r][c], 0, 0, 0);
        acc[r][c] = __builtin_amdgcn_mfma_f32_16x16x32_bf16(Al, Bh[c], acc[r][c], 0, 0, 0);
      }
    }
  }
  // epilogue: C/D layout col=lane&15, row=quad*4+reg (verified m89/m91)
  float asv[4], adv[4];
#pragma unroll
  for (int c = 0; c < 4; c++) {
    int col = bn + wcol + c * 16 + m15;
    asv[c] = att_src[col];
    adv[c] = att_dst[col];
  }
#pragma unroll
  for (int r = 0; r < 4; r++) {
#pragma unroll
    for (int p = 0; p < 4; p++) {
      int grow = bm + wrow + r * 16 + q * 4 + p;
      float s = acc[r][0][p] * asv[0] + acc[r][1][p] * asv[1] +
                acc[r][2][p] * asv[2] + acc[r][3][p] * asv[3];
      float d = acc[r][0][p] * adv[0] + acc[r][1][p] * adv[1] +
                acc[r][2][p] * adv[2] + acc[r][3][p] * adv[3];
#pragma unroll
      for (int o = 1; o < 16; o <<= 1) {
        s += __shfl_xor(s, o, 64);
        d += __shfl_xor(d, o, 64);
      }
      if (grow < M) {
        if (m15 == 0) {
          if constexpr (H == 4) {
            int head = (bn >> 6) + (wcol >> 6);
            a_src[grow * 4 + head] = s;
            a_dst[grow * 4 + head] = d;
          } else {
            atomicAdd(&a_src[grow], s);
            atomicAdd(&a_dst[grow], d);
          }
        }
#pragma unroll
        for (int c = 0; c < 4; c++) {
          int gcol = bn + wcol + c * 16 + m15;
          C16[(size_t)grow * 256 + gcol] = f2bf(acc[r][c][p]);
        }
      }
    }
  }
}

// ---- fully fused aggregate: in-register softmax (max-free), 1 wave/node ----
template <int CH>
__global__ __launch_bounds__(128) void agg_kernel(
    const short* __restrict__ h16, const float* __restrict__ a_src,
    const float* __restrict__ a_dst, const int* __restrict__ offs,
    const int* __restrict__ ssrc, const float* __restrict__ bias,
    float* __restrict__ out, float* __restrict__ z1, float* __restrict__ z2) {
  constexpr int H = 256 / CH;
  int n = blockIdx.x * 2 + (threadIdx.x >> 6);
  int lane = threadIdx.x & 63;
  if (n >= N_NODES) return;
  int head = (4 * lane) / CH;
  int start = offs[n], end = offs[n + 1];
  float adv = a_dst[n * H + head];
  if (z1 != nullptr && lane == 0) { z1[n] = 0.f; z2[n] = 0.f; }
  float l = 0.f;
  float acc0 = 0.f, acc1 = 0.f, acc2 = 0.f, acc3 = 0.f;
  int i = start;
  for (; i + 8 <= end; i += 8) {
    int s[8]; uint2 u[8]; float av[8];
#pragma unroll
    for (int j = 0; j < 8; j++) s[j] = ssrc[i + j];
#pragma unroll
    for (int j = 0; j < 8; j++)
      u[j] = *(const uint2*)(h16 + (size_t)s[j] * 256 + 4 * lane);
#pragma unroll
    for (int j = 0; j < 8; j++) av[j] = a_src[s[j] * H + head];
#pragma unroll
    for (int j = 0; j < 8; j++) {
      float p = __expf(lrelu(av[j] + adv));
      l += p;
      acc0 = fmaf(p, __uint_as_float(u[j].x << 16), acc0);
      acc1 = fmaf(p, __uint_as_float(u[j].x & 0xffff0000u), acc1);
      acc2 = fmaf(p, __uint_as_float(u[j].y << 16), acc2);
      acc3 = fmaf(p, __uint_as_float(u[j].y & 0xffff0000u), acc3);
    }
  }
  for (; i < end; i++) {
    int s = ssrc[i];
    uint2 u = *(const uint2*)(h16 + (size_t)s * 256 + 4 * lane);
    float p = __expf(lrelu(a_src[s * H + head] + adv));
    l += p;
    acc0 = fmaf(p, __uint_as_float(u.x << 16), acc0);
    acc1 = fmaf(p, __uint_as_float(u.x & 0xffff0000u), acc1);
    acc2 = fmaf(p, __uint_as_float(u.y << 16), acc2);
    acc3 = fmaf(p, __uint_as_float(u.y & 0xffff0000u), acc3);
  }
  float ilv = l > 0.f ? 1.f / l : 0.f;
  float4 bv = *(const float4*)(bias + 4 * lane);
  float4 o;
  o.x = fmaxf(fmaf(acc0, ilv, bv.x), 0.f);
  o.y = fmaxf(fmaf(acc1, ilv, bv.y), 0.f);
  o.z = fmaxf(fmaf(acc2, ilv, bv.z), 0.f);
  o.w = fmaxf(fmaf(acc3, ilv, bv.w), 0.f);
  *(float4*)(out + (size_t)n * 256 + 4 * lane) = o;
}

// ---- global mean pool + FC ----
#define POOL_PARTS 16
__global__ __launch_bounds__(256) void pool_partial_kernel(
    const float* __restrict__ h, const int* __restrict__ gstart,
    float* __restrict__ part) {
  int g = blockIdx.x, p = blockIdx.y, t = threadIdx.x;
  int s = gstart[g], e = gstart[g + 1];
  float acc = 0.f;
  for (int n = s + p; n < e; n += POOL_PARTS) acc += h[(size_t)n * 256 + t];
  part[((size_t)g * POOL_PARTS + p) * 256 + t] = acc;
}

__global__ __launch_bounds__(256) void poolfc_kernel(
    const float* __restrict__ part, const int* __restrict__ gstart,
    const float* __restrict__ W, const float* __restrict__ b,
    float* __restrict__ out) {
  int g = blockIdx.x, t = threadIdx.x;
  __shared__ float ps[256];
  float acc = 0.f;
#pragma unroll
  for (int p = 0; p < POOL_PARTS; p++)
    acc += part[((size_t)g * POOL_PARTS + p) * 256 + t];
  int cnt = gstart[g + 1] - gstart[g];
  ps[t] = acc / (float)(cnt > 0 ? cnt : 1);
  __syncthreads();
  float a2 = 0.f;
#pragma unroll 8
  for (int k = 0; k < 256; k++) a2 = fmaf(ps[k], W[k * 256 + t], a2);
  out[g * 256 + t] = fmaxf(a2 + b[t], 0.f);
}

extern "C" void kernel_launch(void* const* d_in, const int* in_sizes, int n_in,
                              void* d_out, int out_size, void* d_ws, size_t ws_size,
                              hipStream_t stream) {
  const float* x      = (const float*)d_in[0];
  const int*   ei     = (const int*)d_in[1];
  const int*   batch  = (const int*)d_in[2];
  const float* W1     = (const float*)d_in[3];
  const float* att_s1 = (const float*)d_in[4];
  const float* att_d1 = (const float*)d_in[5];
  const float* b1     = (const float*)d_in[6];
  const float* W2     = (const float*)d_in[7];
  const float* att_s2 = (const float*)d_in[8];
  const float* att_d2 = (const float*)d_in[9];
  const float* b2     = (const float*)d_in[10];
  const float* Wfc    = (const float*)d_in[11];
  const float* bfc    = (const float*)d_in[12];
  const int* src = ei;
  const int* dst = ei + N_EDGES;
  float* outp = (float*)d_out;

  char* ws = (char*)d_ws;
  size_t off = 0;
  auto alloc = [&](size_t bytes) -> char* {
    char* p = ws + off;
    off += (bytes + 255) & ~(size_t)255;
    return p;
  };
  float* x2_buf = (float*)alloc((size_t)N_NODES * FEAT * 4);
  short* h16    = (short*)alloc((size_t)N_NODES * FEAT * 2);
  float* as_buf = (float*)alloc((size_t)N_NODES * 4 * 4);
  float* ad_buf = (float*)alloc((size_t)N_NODES * 4 * 4);
  float* as2    = (float*)alloc((size_t)N_NODES * 4);
  float* ad2    = (float*)alloc((size_t)N_NODES * 4);
  float* part   = (float*)alloc((size_t)N_GRAPHS * POOL_PARTS * FEAT * 4);
  short* WtH1   = (short*)alloc((size_t)256 * 256 * 2);
  short* WtL1   = (short*)alloc((size_t)256 * 256 * 2);
  short* WtH2   = (short*)alloc((size_t)256 * 256 * 2);
  short* WtL2   = (short*)alloc((size_t)256 * 256 * 2);
  int* cnt    = (int*)alloc((size_t)N_NODES * 4);
  int* offs   = (int*)alloc((size_t)(N_NODES + 1) * 4);
  int* cursor = (int*)alloc((size_t)N_NODES * 4);
  int* ssrc   = (int*)alloc((size_t)N_EDGES * 4);
  int* bsum   = (int*)alloc((size_t)256 * 4);
  int* gstart = (int*)alloc((size_t)(N_GRAPHS + 1) * 4);

  int eb = (N_EDGES + 255) / 256;   // 3125
  int nb = (N_NODES + 255) / 256;   // 196
  int gy = (N_NODES + 127) / 128;   // 391

  hipMemsetAsync(cnt, 0, (size_t)N_NODES * 4, stream);
  wsplit_hist_kernel<<<512 + eb, 256, 0, stream>>>(W1, W2, WtH1, WtL1, WtH2, WtL2,
                                                   dst, cnt);
  scan_partial_kernel<<<nb, 256, 0, stream>>>(cnt, bsum, N_NODES, batch, gstart);
  scan_final_kernel<<<nb, 256, 0, stream>>>(cnt, bsum, offs, cursor, N_NODES, nb);

  dim3 gg(2, gy);
  // layer 1: scatter prologue + gemm + att epilogue
  gemm_mfma_kernel<4><<<gg, 256, 0, stream>>>(x, WtH1, WtL1, h16,
                                              att_s1, att_d1, as_buf, ad_buf,
                                              N_NODES, src, dst, cursor, ssrc);
  agg_kernel<64><<<N_NODES / 2, 128, 0, stream>>>(h16, as_buf, ad_buf, offs, ssrc,
                                                  b1, x2_buf, as2, ad2);
  // layer 2: H=1 (as2/ad2 pre-zeroed by layer-1 agg)
  gemm_mfma_kernel<1><<<gg, 256, 0, stream>>>(x2_buf, WtH2, WtL2, h16,
                                              att_s2, att_d2, as2, ad2,
                                              N_NODES, nullptr, nullptr,
                                              nullptr, nullptr);
  agg_kernel<256><<<N_NODES / 2, 128, 0, stream>>>(h16, as2, ad2, offs, ssrc,
                                                   b2, x2_buf, nullptr, nullptr);
  pool_partial_kernel<<<dim3(N_GRAPHS, POOL_PARTS), 256, 0, stream>>>(x2_buf, gstart, part);
  poolfc_kernel<<<N_GRAPHS, 256, 0, stream>>>(part, gstart, Wfc, bfc, outp);
}

// Round 13
// 427.906 us; speedup vs baseline: 1.1712x; 1.1074x over previous
//
#include <hip/hip_runtime.h>
#include <hip/hip_bf16.h>
#include <cfloat>

#define N_NODES 50000
#define N_EDGES 800000
#define N_GRAPHS 50
#define FEAT 256
#define NEG_SLOPE 0.2f

typedef __attribute__((ext_vector_type(8))) short short8;
typedef __attribute__((ext_vector_type(4))) float floatx4;

__device__ __forceinline__ float lrelu(float e) {
  return e > 0.f ? e : NEG_SLOPE * e;
}
__device__ __forceinline__ short f2bf(float f) {
  __hip_bfloat16 b = __float2bfloat16(f);
  return *(short*)&b;
}
__device__ __forceinline__ float bf2f(short s) {
  unsigned u = ((unsigned)(unsigned short)s) << 16;
  return __uint_as_float(u);
}

// ---- W prep (blocks 0..511) + dst histogram (blocks 512..) ----
// cnt pre-zeroed by memsetAsync (block order undefined).
__global__ __launch_bounds__(256) void wsplit_hist_kernel(
    const float* __restrict__ W1, const float* __restrict__ W2,
    short* __restrict__ H1, short* __restrict__ L1,
    short* __restrict__ H2, short* __restrict__ L2,
    const int* __restrict__ dst, int* __restrict__ cnt) {
  int b = blockIdx.x, t = threadIdx.x;
  if (b < 512) {
    const float* W = (b < 256) ? W1 : W2;
    short* Hp = (b < 256) ? H1 : H2;
    short* Lp = (b < 256) ? L1 : L2;
    int k = b & 255;
    float v = W[k * 256 + t];
    short h = f2bf(v);
    Hp[t * 256 + k] = h;
    Lp[t * 256 + k] = f2bf(v - bf2f(h));
  } else {
    int e = (b - 512) * 256 + t;
    if (e < N_EDGES) atomicAdd(&cnt[dst[e]], 1);
  }
}

// ---- block reduction of cnt -> bsum; block 0 also computes graph bounds ----
__global__ __launch_bounds__(256) void scan_partial_kernel(
    const int* __restrict__ cnt, int* __restrict__ bsum, int n,
    const int* __restrict__ batch, int* __restrict__ gstart) {
  __shared__ int buf[256];
  int t = threadIdx.x;
  int i = blockIdx.x * 256 + t;
  buf[t] = (i < n) ? cnt[i] : 0;
  __syncthreads();
  for (int off = 128; off >= 1; off >>= 1) {
    if (t < off) buf[t] += buf[t + off];
    __syncthreads();
  }
  if (t == 0) bsum[blockIdx.x] = buf[0];
  if (blockIdx.x == 0 && t <= N_GRAPHS) {
    int lo = 0, hi = N_NODES;
    while (lo < hi) {
      int mid = (lo + hi) >> 1;
      if (batch[mid] < t) lo = mid + 1; else hi = mid;
    }
    gstart[t] = lo;
  }
}

// ---- final scan: each block re-scans the block-sums in LDS ----
__global__ __launch_bounds__(256) void scan_final_kernel(
    const int* __restrict__ cnt, const int* __restrict__ bsum,
    int* __restrict__ offs, int* __restrict__ cursor, int n, int nb) {
  __shared__ int buf[256], sb[256];
  int t = threadIdx.x;
  int i = blockIdx.x * 256 + t;
  int v = (i < n) ? cnt[i] : 0;
  buf[t] = v;
  sb[t] = (t < nb) ? bsum[t] : 0;
  __syncthreads();
  for (int off = 1; off < 256; off <<= 1) {
    int y1 = (t >= off) ? buf[t - off] : 0;
    int y2 = (t >= off) ? sb[t - off] : 0;
    __syncthreads();
    buf[t] += y1;
    sb[t] += y2;
    __syncthreads();
  }
  int carry = (blockIdx.x > 0) ? sb[blockIdx.x - 1] : 0;
  int excl = buf[t] - v + carry;
  if (i < n) { offs[i] = excl; cursor[i] = excl; }
  if (blockIdx.x == 0 && t == 0) offs[N_NODES] = sb[nb - 1];
}

// ---- MFMA GEMM + fused attention dots; scatter blocks INTERLEAVED ----
// R8 4-buffer LDS structure (best measured). When scatter==true, odd
// blockIdx.y rows are counting-sort scatter blocks (1024 edges each) —
// interleaved 2:2 with gemm blocks in dispatch order so their VMEM-atomic
// waves co-schedule with MFMA waves on the same CUs (m114 overlap).
template <int H, bool SCATTER>
__global__ __launch_bounds__(256) void gemm_mfma_kernel(
    const float* __restrict__ A, const short* __restrict__ WtH,
    const short* __restrict__ WtL, short* __restrict__ C16,
    const float* __restrict__ att_src, const float* __restrict__ att_dst,
    float* __restrict__ a_src, float* __restrict__ a_dst, int M,
    const int* __restrict__ esrc, const int* __restrict__ edst,
    int* __restrict__ cursor, int* __restrict__ ssrc) {
  int t = threadIdx.x;
  int yb = blockIdx.y;
  if constexpr (SCATTER) {
    if (yb & 1) {
      int part = (yb >> 1) * 2 + blockIdx.x;  // 0..781
      int base = part * 1024 + t;
#pragma unroll
      for (int j = 0; j < 4; j++) {
        int e = base + j * 256;
        if (e < N_EDGES) {
          int d = edst[e];
          int pos = atomicAdd(&cursor[d], 1);
          ssrc[pos] = esrc[e];
        }
      }
      return;
    }
    yb >>= 1;
  }
  __shared__ short AsH[128][40], AsL[128][40], BsH[128][40], BsL[128][40];
  int bm = yb * 128, bn = blockIdx.x * 128;
  int w = t >> 6, lane = t & 63;
  int wrow = (w & 1) * 64, wcol = (w >> 1) * 64;
  int m15 = lane & 15, q = lane >> 4;
  int sr = t >> 1, sk = (t & 1) * 16;
  floatx4 acc[4][4] = {};
  int arow = bm + sr;
  for (int k0 = 0; k0 < 256; k0 += 32) {
    float4 a0 = make_float4(0.f, 0.f, 0.f, 0.f), a1 = a0, a2 = a0, a3 = a0;
    if (arow < M) {
      const float* Ap = A + (size_t)arow * 256 + k0 + sk;
      a0 = *(const float4*)(Ap + 0);
      a1 = *(const float4*)(Ap + 4);
      a2 = *(const float4*)(Ap + 8);
      a3 = *(const float4*)(Ap + 12);
    }
    const short* BHp = WtH + (size_t)(bn + sr) * 256 + k0 + sk;
    const short* BLp = WtL + (size_t)(bn + sr) * 256 + k0 + sk;
    int4 bh0 = *(const int4*)(BHp);
    int4 bh1 = *(const int4*)(BHp + 8);
    int4 bl0 = *(const int4*)(BLp);
    int4 bl1 = *(const int4*)(BLp + 8);
    float af[16];
    *(float4*)&af[0] = a0; *(float4*)&af[4] = a1;
    *(float4*)&af[8] = a2; *(float4*)&af[12] = a3;
    short th[16], tl[16];
#pragma unroll
    for (int j = 0; j < 16; j++) {
      short h = f2bf(af[j]);
      th[j] = h;
      tl[j] = f2bf(af[j] - bf2f(h));
    }
    __syncthreads();
    *(int4*)&AsH[sr][sk + 0] = *(int4*)&th[0];
    *(int4*)&AsH[sr][sk + 8] = *(int4*)&th[8];
    *(int4*)&AsL[sr][sk + 0] = *(int4*)&tl[0];
    *(int4*)&AsL[sr][sk + 8] = *(int4*)&tl[8];
    *(int4*)&BsH[sr][sk + 0] = bh0;
    *(int4*)&BsH[sr][sk + 8] = bh1;
    *(int4*)&BsL[sr][sk + 0] = bl0;
    *(int4*)&BsL[sr][sk + 8] = bl1;
    __syncthreads();
    short8 Bh[4], Bl[4];
#pragma unroll
    for (int c = 0; c < 4; c++) {
      Bh[c] = *(const short8*)&BsH[wcol + c * 16 + m15][q * 8];
      Bl[c] = *(const short8*)&BsL[wcol + c * 16 + m15][q * 8];
    }
#pragma unroll
    for (int r = 0; r < 4; r++) {
      short8 Ah = *(const short8*)&AsH[wrow + r * 16 + m15][q * 8];
      short8 Al = *(const short8*)&AsL[wrow + r * 16 + m15][q * 8];
#pragma unroll
      for (int c = 0; c < 4; c++) {
        acc[r][c] = __builtin_amdgcn_mfma_f32_16x16x32_bf16(Ah, Bh[c], acc[r][c], 0, 0, 0);
        acc[r][c] = __builtin_amdgcn_mfma_f32_16x16x32_bf16(Ah, Bl[c], acc[r][c], 0, 0, 0);
        acc[r][c] = __builtin_amdgcn_mfma_f32_16x16x32_bf16(Al, Bh[c], acc[r][c], 0, 0, 0);
      }
    }
  }
  float asv[4], adv[4];
#pragma unroll
  for (int c = 0; c < 4; c++) {
    int col = bn + wcol + c * 16 + m15;
    asv[c] = att_src[col];
    adv[c] = att_dst[col];
  }
#pragma unroll
  for (int r = 0; r < 4; r++) {
#pragma unroll
    for (int p = 0; p < 4; p++) {
      int grow = bm + wrow + r * 16 + q * 4 + p;
      float s = acc[r][0][p] * asv[0] + acc[r][1][p] * asv[1] +
                acc[r][2][p] * asv[2] + acc[r][3][p] * asv[3];
      float d = acc[r][0][p] * adv[0] + acc[r][1][p] * adv[1] +
                acc[r][2][p] * adv[2] + acc[r][3][p] * adv[3];
#pragma unroll
      for (int o = 1; o < 16; o <<= 1) {
        s += __shfl_xor(s, o, 64);
        d += __shfl_xor(d, o, 64);
      }
      if (grow < M) {
        if (m15 == 0) {
          if constexpr (H == 4) {
            int head = (bn >> 6) + (wcol >> 6);
            a_src[grow * 4 + head] = s;
            a_dst[grow * 4 + head] = d;
          } else {
            atomicAdd(&a_src[grow], s);
            atomicAdd(&a_dst[grow], d);
          }
        }
#pragma unroll
        for (int c = 0; c < 4; c++) {
          int gcol = bn + wcol + c * 16 + m15;
          C16[(size_t)grow * 256 + gcol] = f2bf(acc[r][c][p]);
        }
      }
    }
  }
}

// ---- fully fused aggregate: in-register softmax (max-free) ----
// 256-thread blocks = 4 waves = 4 nodes (doubles resident waves vs 128).
template <int CH>
__global__ __launch_bounds__(256) void agg_kernel(
    const short* __restrict__ h16, const float* __restrict__ a_src,
    const float* __restrict__ a_dst, const int* __restrict__ offs,
    const int* __restrict__ ssrc, const float* __restrict__ bias,
    float* __restrict__ out, float* __restrict__ z1, float* __restrict__ z2) {
  constexpr int H = 256 / CH;
  int n = blockIdx.x * 4 + (threadIdx.x >> 6);
  int lane = threadIdx.x & 63;
  if (n >= N_NODES) return;
  int head = (4 * lane) / CH;
  int start = offs[n], end = offs[n + 1];
  float adv = a_dst[n * H + head];
  if (z1 != nullptr && lane == 0) { z1[n] = 0.f; z2[n] = 0.f; }
  float l = 0.f;
  float acc0 = 0.f, acc1 = 0.f, acc2 = 0.f, acc3 = 0.f;
  int i = start;
  for (; i + 8 <= end; i += 8) {
    int s[8]; uint2 u[8]; float av[8];
#pragma unroll
    for (int j = 0; j < 8; j++) s[j] = ssrc[i + j];
#pragma unroll
    for (int j = 0; j < 8; j++)
      u[j] = *(const uint2*)(h16 + (size_t)s[j] * 256 + 4 * lane);
#pragma unroll
    for (int j = 0; j < 8; j++) av[j] = a_src[s[j] * H + head];
#pragma unroll
    for (int j = 0; j < 8; j++) {
      float p = __expf(lrelu(av[j] + adv));
      l += p;
      acc0 = fmaf(p, __uint_as_float(u[j].x << 16), acc0);
      acc1 = fmaf(p, __uint_as_float(u[j].x & 0xffff0000u), acc1);
      acc2 = fmaf(p, __uint_as_float(u[j].y << 16), acc2);
      acc3 = fmaf(p, __uint_as_float(u[j].y & 0xffff0000u), acc3);
    }
  }
  for (; i < end; i++) {
    int s = ssrc[i];
    uint2 u = *(const uint2*)(h16 + (size_t)s * 256 + 4 * lane);
    float p = __expf(lrelu(a_src[s * H + head] + adv));
    l += p;
    acc0 = fmaf(p, __uint_as_float(u.x << 16), acc0);
    acc1 = fmaf(p, __uint_as_float(u.x & 0xffff0000u), acc1);
    acc2 = fmaf(p, __uint_as_float(u.y << 16), acc2);
    acc3 = fmaf(p, __uint_as_float(u.y & 0xffff0000u), acc3);
  }
  float ilv = l > 0.f ? 1.f / l : 0.f;
  float4 bv = *(const float4*)(bias + 4 * lane);
  float4 o;
  o.x = fmaxf(fmaf(acc0, ilv, bv.x), 0.f);
  o.y = fmaxf(fmaf(acc1, ilv, bv.y), 0.f);
  o.z = fmaxf(fmaf(acc2, ilv, bv.z), 0.f);
  o.w = fmaxf(fmaf(acc3, ilv, bv.w), 0.f);
  *(float4*)(out + (size_t)n * 256 + 4 * lane) = o;
}

// ---- global mean pool + FC ----
#define POOL_PARTS 16
__global__ __launch_bounds__(256) void pool_partial_kernel(
    const float* __restrict__ h, const int* __restrict__ gstart,
    float* __restrict__ part) {
  int g = blockIdx.x, p = blockIdx.y, t = threadIdx.x;
  int s = gstart[g], e = gstart[g + 1];
  float acc = 0.f;
  for (int n = s + p; n < e; n += POOL_PARTS) acc += h[(size_t)n * 256 + t];
  part[((size_t)g * POOL_PARTS + p) * 256 + t] = acc;
}

__global__ __launch_bounds__(256) void poolfc_kernel(
    const float* __restrict__ part, const int* __restrict__ gstart,
    const float* __restrict__ W, const float* __restrict__ b,
    float* __restrict__ out) {
  int g = blockIdx.x, t = threadIdx.x;
  __shared__ float ps[256];
  float acc = 0.f;
#pragma unroll
  for (int p = 0; p < POOL_PARTS; p++)
    acc += part[((size_t)g * POOL_PARTS + p) * 256 + t];
  int cnt = gstart[g + 1] - gstart[g];
  ps[t] = acc / (float)(cnt > 0 ? cnt : 1);
  __syncthreads();
  float a2 = 0.f;
#pragma unroll 8
  for (int k = 0; k < 256; k++) a2 = fmaf(ps[k], W[k * 256 + t], a2);
  out[g * 256 + t] = fmaxf(a2 + b[t], 0.f);
}

extern "C" void kernel_launch(void* const* d_in, const int* in_sizes, int n_in,
                              void* d_out, int out_size, void* d_ws, size_t ws_size,
                              hipStream_t stream) {
  const float* x      = (const float*)d_in[0];
  const int*   ei     = (const int*)d_in[1];
  const int*   batch  = (const int*)d_in[2];
  const float* W1     = (const float*)d_in[3];
  const float* att_s1 = (const float*)d_in[4];
  const float* att_d1 = (const float*)d_in[5];
  const float* b1     = (const float*)d_in[6];
  const float* W2     = (const float*)d_in[7];
  const float* att_s2 = (const float*)d_in[8];
  const float* att_d2 = (const float*)d_in[9];
  const float* b2     = (const float*)d_in[10];
  const float* Wfc    = (const float*)d_in[11];
  const float* bfc    = (const float*)d_in[12];
  const int* src = ei;
  const int* dst = ei + N_EDGES;
  float* outp = (float*)d_out;

  char* ws = (char*)d_ws;
  size_t off = 0;
  auto alloc = [&](size_t bytes) -> char* {
    char* p = ws + off;
    off += (bytes + 255) & ~(size_t)255;
    return p;
  };
  float* x2_buf = (float*)alloc((size_t)N_NODES * FEAT * 4);
  short* h16    = (short*)alloc((size_t)N_NODES * FEAT * 2);
  float* as_buf = (float*)alloc((size_t)N_NODES * 4 * 4);
  float* ad_buf = (float*)alloc((size_t)N_NODES * 4 * 4);
  float* as2    = (float*)alloc((size_t)N_NODES * 4);
  float* ad2    = (float*)alloc((size_t)N_NODES * 4);
  float* part   = (float*)alloc((size_t)N_GRAPHS * POOL_PARTS * FEAT * 4);
  short* WtH1   = (short*)alloc((size_t)256 * 256 * 2);
  short* WtL1   = (short*)alloc((size_t)256 * 256 * 2);
  short* WtH2   = (short*)alloc((size_t)256 * 256 * 2);
  short* WtL2   = (short*)alloc((size_t)256 * 256 * 2);
  int* cnt    = (int*)alloc((size_t)N_NODES * 4);
  int* offs   = (int*)alloc((size_t)(N_NODES + 1) * 4);
  int* cursor = (int*)alloc((size_t)N_NODES * 4);
  int* ssrc   = (int*)alloc((size_t)N_EDGES * 4);
  int* bsum   = (int*)alloc((size_t)256 * 4);
  int* gstart = (int*)alloc((size_t)(N_GRAPHS + 1) * 4);

  int eb = (N_EDGES + 255) / 256;   // 3125
  int nb = (N_NODES + 255) / 256;   // 196
  int gy = (N_NODES + 127) / 128;   // 391

  hipMemsetAsync(cnt, 0, (size_t)N_NODES * 4, stream);
  wsplit_hist_kernel<<<512 + eb, 256, 0, stream>>>(W1, W2, WtH1, WtL1, WtH2, WtL2,
                                                   dst, cnt);
  scan_partial_kernel<<<nb, 256, 0, stream>>>(cnt, bsum, N_NODES, batch, gstart);
  scan_final_kernel<<<nb, 256, 0, stream>>>(cnt, bsum, offs, cursor, N_NODES, nb);

  // layer 1: gemm + att epilogue, scatter blocks interleaved (odd y rows)
  dim3 g1(2, 2 * gy);
  gemm_mfma_kernel<4, true><<<g1, 256, 0, stream>>>(x, WtH1, WtL1, h16,
                                                    att_s1, att_d1, as_buf, ad_buf,
                                                    N_NODES, src, dst, cursor, ssrc);
  agg_kernel<64><<<(N_NODES + 3) / 4, 256, 0, stream>>>(h16, as_buf, ad_buf, offs,
                                                        ssrc, b1, x2_buf, as2, ad2);
  // layer 2: H=1 (as2/ad2 pre-zeroed by layer-1 agg)
  dim3 g2(2, gy);
  gemm_mfma_kernel<1, false><<<g2, 256, 0, stream>>>(x2_buf, WtH2, WtL2, h16,
                                                     att_s2, att_d2, as2, ad2,
                                                     N_NODES, nullptr, nullptr,
                                                     nullptr, nullptr);
  agg_kernel<256><<<(N_NODES + 3) / 4, 256, 0, stream>>>(h16, as2, ad2, offs,
                                                         ssrc, b2, x2_buf,
                                                         nullptr, nullptr);
  pool_partial_kernel<<<dim3(N_GRAPHS, POOL_PARTS), 256, 0, stream>>>(x2_buf, gstart, part);
  poolfc_kernel<<<N_GRAPHS, 256, 0, stream>>>(part, gstart, Wfc, bfc, outp);
}